// Round 3
// baseline (4048.182 us; speedup 1.0000x reference)
//
#include <hip/hip_runtime.h>
#include <cstddef>

typedef unsigned short ushort_t;
typedef unsigned int uint_t;
typedef __attribute__((ext_vector_type(8))) short bf16x8;
typedef __attribute__((ext_vector_type(4))) float f32x4;

constexpr int kB  = 128;
constexpr int kT  = 32;
constexpr int kN  = 196;
constexpr int kH  = 1024;

constexpr int ARENA_BYTES = 55296;  // hgemm BK=64 staging (36864 A + 18432 W); eps 33280 fits

__device__ __forceinline__ float fsigmoid(float x) { return 1.f / (1.f + __expf(-x)); }
__device__ __forceinline__ float ftanh(float x)    { return 1.f - 2.f / (__expf(2.f * x) + 1.f); }
__device__ __forceinline__ ushort_t f2bf(float f) {
    uint_t u = __float_as_uint(f);
    return (ushort_t)((u + 0x7fffu + ((u >> 16) & 1u)) >> 16);
}

// ---------------------------------------------------------------------------
// Pre-pass pack / cast kernels (unchanged)
// ---------------------------------------------------------------------------
__global__ __launch_bounds__(256) void wf_transpose(
    const float* __restrict__ Wsrc, ushort_t* __restrict__ dst)
{
    __shared__ float t[64][65];
    const int k0 = blockIdx.x * 64, a0 = blockIdx.y * 64;
    const int c = threadIdx.x & 15, r0 = threadIdx.x >> 4;
#pragma unroll
    for (int i = 0; i < 4; ++i) {
        const int r = r0 + i * 16;
        const float4 v = *(const float4*)(Wsrc + (size_t)(k0 + r) * 1024 + a0 + c * 4);
        t[r][c * 4 + 0] = v.x; t[r][c * 4 + 1] = v.y;
        t[r][c * 4 + 2] = v.z; t[r][c * 4 + 3] = v.w;
    }
    __syncthreads();
#pragma unroll
    for (int i = 0; i < 4; ++i) {
        const int r = r0 + i * 16;
        ushort4 h;
        h.x = f2bf(t[c * 4 + 0][r]); h.y = f2bf(t[c * 4 + 1][r]);
        h.z = f2bf(t[c * 4 + 2][r]); h.w = f2bf(t[c * 4 + 3][r]);
        *(ushort4*)&dst[(size_t)(a0 + r) * 1024 + k0 + c * 4] = h;
    }
}

__global__ __launch_bounds__(256) void pack_whh0(
    const float* __restrict__ Whh0, ushort_t* __restrict__ Wbig)
{
    const int idx = blockIdx.x * 256 + threadIdx.x;
    const int j = idx >> 8, k4 = (idx & 255) * 4;
    const int u = j >> 2, g = j & 3;
    const float4 v = *(const float4*)(Whh0 + (size_t)(g * 1024 + u) * 1024 + k4);
    ushort4 h;
    h.x = f2bf(v.x); h.y = f2bf(v.y); h.z = f2bf(v.z); h.w = f2bf(v.w);
    *(ushort4*)&Wbig[(size_t)(1024 + j) * 1024 + k4] = h;
}

__global__ __launch_bounds__(256) void pack_w1sum(
    const float* __restrict__ Wih1, const float* __restrict__ Whh1,
    ushort_t* __restrict__ Wbig)
{
    const int idx = blockIdx.x * 256 + threadIdx.x;
    const int j = idx >> 8, k4 = (idx & 255) * 4;
    const int u = j >> 2, g = j & 3;
    const size_t o = (size_t)(g * 1024 + u) * 1024 + k4;
    const float4 a = *(const float4*)(Wih1 + o);
    const float4 b = *(const float4*)(Whh1 + o);
    ushort4 h;
    h.x = f2bf(a.x + b.x); h.y = f2bf(a.y + b.y);
    h.z = f2bf(a.z + b.z); h.w = f2bf(a.w + b.w);
    *(ushort4*)&Wbig[(size_t)(5120 + j) * 1024 + k4] = h;
}

__global__ __launch_bounds__(256) void pack_w0cat(
    const float* __restrict__ Wih0, ushort_t* __restrict__ W0cat)
{
    const int idx = blockIdx.x * 256 + threadIdx.x;
    const int j = idx >> 9, k4 = (idx & 511) * 4;
    const int u = j >> 2, g = j & 3;
    const int srccol = (k4 < 1024) ? (k4 + 1024) : (k4 - 1024);
    const float4 v = *(const float4*)(Wih0 + (size_t)(g * 1024 + u) * 2048 + srccol);
    ushort4 h;
    h.x = f2bf(v.x); h.y = f2bf(v.y); h.z = f2bf(v.z); h.w = f2bf(v.w);
    *(ushort4*)&W0cat[(size_t)j * 2048 + k4] = h;
}

__global__ __launch_bounds__(256) void cast_bf(
    const float* __restrict__ src, ushort_t* __restrict__ dst)
{
    const size_t idx = ((size_t)blockIdx.x * 256 + threadIdx.x) * 4;
    const float4 v = *(const float4*)(src + idx);
    ushort4 h;
    h.x = f2bf(v.x); h.y = f2bf(v.y); h.z = f2bf(v.z); h.w = f2bf(v.w);
    *(ushort4*)&dst[idx] = h;
}

// ---------------------------------------------------------------------------
// fproj = bf16(feats @ Wf + b_att). 128x128 tile, BK=32, dbuf, single barrier.
// Epilogue stages C in LDS (reusing dead staging buffers) -> full-line stores.
// ---------------------------------------------------------------------------
template<int BF>
__global__ __launch_bounds__(256) void fproj_mfma(
    const float* __restrict__ featsf, const ushort_t* __restrict__ featsbf,
    const ushort_t* __restrict__ WfT,
    const float* __restrict__ bias, ushort_t* __restrict__ fprojbf)
{
    __shared__ alignas(16) char farena[40960];
    ushort_t* As = (ushort_t*)farena;    // [2][128*40]
    ushort_t* Bs = As + 2 * 5120;        // [2][128*40]
    ushort_t* Cs = (ushort_t*)farena;    // [128][136] (reused after K-loop)

    const int tid = threadIdx.x;
    const int n0 = blockIdx.x * 128, m0 = blockIdx.y * 128;
    const int lane = tid & 63, w = tid >> 6;
    const int wm = (w & 1) * 64, wn = (w >> 1) * 64;
    const int lr = lane & 15, quad = lane >> 4;

    const int xrow0 = tid >> 2, xrow1 = 64 + (tid >> 2);
    const int xkc = (tid & 3) * 8;

    f32x4 acc[4][4];
#pragma unroll
    for (int i = 0; i < 4; ++i)
#pragma unroll
        for (int j = 0; j < 4; ++j)
            acc[i][j] = (f32x4){0.f, 0.f, 0.f, 0.f};

    uint4 a0r, a1r, b0r, b1r;
    float4 f00, f01, f10, f11;

    auto LOAD = [&](int k0) {
        if (BF) {
            a0r = *(const uint4*)&featsbf[(size_t)(m0 + xrow0) * 1024 + k0 + xkc];
            a1r = *(const uint4*)&featsbf[(size_t)(m0 + xrow1) * 1024 + k0 + xkc];
        } else {
            f00 = *(const float4*)&featsf[(size_t)(m0 + xrow0) * 1024 + k0 + xkc];
            f01 = *(const float4*)&featsf[(size_t)(m0 + xrow0) * 1024 + k0 + xkc + 4];
            f10 = *(const float4*)&featsf[(size_t)(m0 + xrow1) * 1024 + k0 + xkc];
            f11 = *(const float4*)&featsf[(size_t)(m0 + xrow1) * 1024 + k0 + xkc + 4];
        }
        b0r = *(const uint4*)&WfT[(size_t)(n0 + xrow0) * 1024 + k0 + xkc];
        b1r = *(const uint4*)&WfT[(size_t)(n0 + xrow1) * 1024 + k0 + xkc];
    };
    auto WRITE = [&](int buf) {
        if (BF) {
            *(uint4*)&As[buf * 5120 + xrow0 * 40 + xkc] = a0r;
            *(uint4*)&As[buf * 5120 + xrow1 * 40 + xkc] = a1r;
        } else {
            ushort4 h;
            h.x = f2bf(f00.x); h.y = f2bf(f00.y); h.z = f2bf(f00.z); h.w = f2bf(f00.w);
            *(ushort4*)&As[buf * 5120 + xrow0 * 40 + xkc] = h;
            h.x = f2bf(f01.x); h.y = f2bf(f01.y); h.z = f2bf(f01.z); h.w = f2bf(f01.w);
            *(ushort4*)&As[buf * 5120 + xrow0 * 40 + xkc + 4] = h;
            h.x = f2bf(f10.x); h.y = f2bf(f10.y); h.z = f2bf(f10.z); h.w = f2bf(f10.w);
            *(ushort4*)&As[buf * 5120 + xrow1 * 40 + xkc] = h;
            h.x = f2bf(f11.x); h.y = f2bf(f11.y); h.z = f2bf(f11.z); h.w = f2bf(f11.w);
            *(ushort4*)&As[buf * 5120 + xrow1 * 40 + xkc + 4] = h;
        }
        *(uint4*)&Bs[buf * 5120 + xrow0 * 40 + xkc] = b0r;
        *(uint4*)&Bs[buf * 5120 + xrow1 * 40 + xkc] = b1r;
    };

    LOAD(0); WRITE(0); __syncthreads();
    int cur = 0;
    for (int k0 = 32; k0 <= 1024; k0 += 32) {
        const bool more = (k0 < 1024);
        if (more) LOAD(k0);
        bf16x8 af[4], bb[4];
#pragma unroll
        for (int mf = 0; mf < 4; ++mf)
            af[mf] = *(const bf16x8*)&As[cur * 5120 + (wm + mf * 16 + lr) * 40 + quad * 8];
#pragma unroll
        for (int nf = 0; nf < 4; ++nf)
            bb[nf] = *(const bf16x8*)&Bs[cur * 5120 + (wn + nf * 16 + lr) * 40 + quad * 8];
#pragma unroll
        for (int mf = 0; mf < 4; ++mf)
#pragma unroll
            for (int nf = 0; nf < 4; ++nf)
                acc[mf][nf] = __builtin_amdgcn_mfma_f32_16x16x32_bf16(
                    af[mf], bb[nf], acc[mf][nf], 0, 0, 0);
        if (more) WRITE(cur ^ 1);
        __syncthreads();
        cur ^= 1;
    }

    // stage C tile (bias added) in LDS, then full-line global stores
#pragma unroll
    for (int nf = 0; nf < 4; ++nf) {
        const int n = wn + nf * 16 + lr;
        const float bn = bias[n0 + n];
#pragma unroll
        for (int mf = 0; mf < 4; ++mf)
#pragma unroll
            for (int r = 0; r < 4; ++r) {
                const int m = wm + mf * 16 + quad * 4 + r;
                Cs[m * 136 + n] = f2bf(acc[mf][nf][r] + bn);
            }
    }
    __syncthreads();
#pragma unroll
    for (int p = 0; p < 8; ++p) {
        const int row = p * 16 + (tid >> 4);
        const int c8 = (tid & 15) * 8;
        const uint4 v = *(const uint4*)&Cs[row * 136 + c8];
        *(uint4*)&fprojbf[(size_t)(m0 + row) * 1024 + n0 + c8] = v;
    }
}

// ---------------------------------------------------------------------------
// phase_hgemm: Y = h_t(bf16) @ Wbig[9216,1024]^rowmajor. Tile 128M x 64N,
// BK=64 (16 serial iters), dbuf, single barrier per iter.
// ---------------------------------------------------------------------------
__device__ __forceinline__ void phase_hgemm(
    char* arena, int job, int tstep,
    const ushort_t* __restrict__ hbf, const ushort_t* __restrict__ Wbig,
    const float* __restrict__ cbuf,
    const float* __restrict__ bih1, const float* __restrict__ bhh1,
    float* __restrict__ hwh, float* __restrict__ Ypart,
    float* __restrict__ out)
{
    ushort_t* xs  = (ushort_t*)arena;   // [2][128*72]
    ushort_t* wsB = xs + 2 * 9216;      // [2][64*72]
    float*    eps = (float*)arena;      // [128*65], reused after K-loop

    const int tid = threadIdx.x;
    const int n0 = job * 64;
    const int lane = tid & 63, w = tid >> 6;
    const int wm = (w & 1) * 64, wn = (w >> 1) * 32;
    const int lr = lane & 15, quad = lane >> 4;

    const int arow = tid >> 1, acol = (tid & 1) * 32;
    const int wrow = tid >> 2, wcol = (tid & 3) * 16;

    f32x4 acc[4][2];
#pragma unroll
    for (int i = 0; i < 4; ++i) {
        acc[i][0] = (f32x4){0.f, 0.f, 0.f, 0.f};
        acc[i][1] = (f32x4){0.f, 0.f, 0.f, 0.f};
    }

    uint4 xr[4], wr[2];
    auto LOAD = [&](int k0) {
#pragma unroll
        for (int j = 0; j < 4; ++j)
            xr[j] = *(const uint4*)&hbf[(size_t)arow * 1024 + k0 + acol + j * 8];
#pragma unroll
        for (int j = 0; j < 2; ++j)
            wr[j] = *(const uint4*)&Wbig[(size_t)(n0 + wrow) * 1024 + k0 + wcol + j * 8];
    };
    auto WRITE = [&](int buf) {
#pragma unroll
        for (int j = 0; j < 4; ++j)
            *(uint4*)&xs[buf * 9216 + arow * 72 + acol + j * 8] = xr[j];
#pragma unroll
        for (int j = 0; j < 2; ++j)
            *(uint4*)&wsB[buf * 4608 + wrow * 72 + wcol + j * 8] = wr[j];
    };

    LOAD(0); WRITE(0); __syncthreads();
    int cur = 0;
    for (int k0 = 64; k0 <= 1024; k0 += 64) {
        const bool more = (k0 < 1024);
        if (more) LOAD(k0);
        bf16x8 af[2][4], bb[2][2];
#pragma unroll
        for (int ks = 0; ks < 2; ++ks) {
#pragma unroll
            for (int mf = 0; mf < 4; ++mf)
                af[ks][mf] = *(const bf16x8*)&xs[cur * 9216 + (wm + mf * 16 + lr) * 72 + ks * 32 + quad * 8];
#pragma unroll
            for (int nf = 0; nf < 2; ++nf)
                bb[ks][nf] = *(const bf16x8*)&wsB[cur * 4608 + (wn + nf * 16 + lr) * 72 + ks * 32 + quad * 8];
        }
#pragma unroll
        for (int ks = 0; ks < 2; ++ks)
#pragma unroll
            for (int mf = 0; mf < 4; ++mf)
#pragma unroll
                for (int nf = 0; nf < 2; ++nf)
                    acc[mf][nf] = __builtin_amdgcn_mfma_f32_16x16x32_bf16(
                        af[ks][mf], bb[ks][nf], acc[mf][nf], 0, 0, 0);
        if (more) WRITE(cur ^ 1);
        __syncthreads();
        cur ^= 1;
    }

    if (n0 < 5120) {
        float* dst = (n0 < 1024) ? hwh : Ypart;
        const int stride = (n0 < 1024) ? 1024 : 4096;
        const int nbase = (n0 < 1024) ? n0 : (n0 - 1024);
#pragma unroll
        for (int mf = 0; mf < 4; ++mf)
#pragma unroll
            for (int nf = 0; nf < 2; ++nf)
#pragma unroll
                for (int r = 0; r < 4; ++r) {
                    const int m = wm + mf * 16 + quad * 4 + r;
                    const int n = nbase + wn + nf * 16 + lr;
                    dst[(size_t)m * stride + n] = acc[mf][nf][r];
                }
    } else {
#pragma unroll
        for (int mf = 0; mf < 4; ++mf)
#pragma unroll
            for (int nf = 0; nf < 2; ++nf)
#pragma unroll
                for (int r = 0; r < 4; ++r)
                    eps[(wm + mf * 16 + quad * 4 + r) * 65 + (wn + nf * 16 + lr)] = acc[mf][nf][r];
        __syncthreads();
        if (tstep >= 1) {
#pragma unroll
            for (int i = 0; i < 8; ++i) {
                const int cid = i * 256 + tid;
                const int b = cid & 127, ulc = cid >> 7;
                const int u = ((n0 - 5120) >> 2) + ulc;
                const float iv = fsigmoid(eps[b * 65 + ulc * 4 + 0] + bih1[u]        + bhh1[u]);
                const float fv = fsigmoid(eps[b * 65 + ulc * 4 + 1] + bih1[1024 + u] + bhh1[1024 + u]);
                const float gv = ftanh   (eps[b * 65 + ulc * 4 + 2] + bih1[2048 + u] + bhh1[2048 + u]);
                const float ov = fsigmoid(eps[b * 65 + ulc * 4 + 3] + bih1[3072 + u] + bhh1[3072 + u]);
                const float cp = cbuf[(size_t)b * 1024 + u];
                const float cn = fv * cp + iv * gv;
                out[((size_t)b * kT + (tstep - 1)) * 1024 + u] = ov * ftanh(cn);
            }
        }
    }
}

__global__ __launch_bounds__(256) void hgemm_A(
    const ushort_t* __restrict__ hbf, const ushort_t* __restrict__ Wbig,
    const float* __restrict__ cbuf,
    const float* __restrict__ bih1, const float* __restrict__ bhh1,
    float* __restrict__ hwh, float* __restrict__ Ypart,
    float* __restrict__ out, int tstep, int job_base)
{
    __shared__ alignas(16) char arena[ARENA_BYTES];
    phase_hgemm(arena, blockIdx.x + job_base, tstep, hbf, Wbig, cbuf,
                bih1, bhh1, hwh, Ypart, out);
}

// ---------------------------------------------------------------------------
// Fused scores + softmax + attn: one block per batch row b, 1024 threads.
//  phase1: 16 waves each compute ~12 score rows (verbatim per-wave body)
//  phase2: softmax over 196 scores (16-wave partials; bit-identical result)
//  phase3: attn weighted sum, tid<512, verbatim per-thread loop
// ---------------------------------------------------------------------------
__global__ __launch_bounds__(1024) void scores_attn(
    const ushort_t* __restrict__ fprojbf, const float* __restrict__ hwh,
    const float* __restrict__ vvec, const ushort_t* __restrict__ featsbf,
    ushort_t* __restrict__ attnbf)
{
    __shared__ float scores_s[196];
    __shared__ float alpha_s[200];
    __shared__ float red[32];
    const int b = blockIdx.x;
    const int tid = threadIdx.x, lane = tid & 63, w = tid >> 6;  // w: 0..15

    // ---- phase 1: scores ----
    {
        float hw[16], vr[16];
        const int a0 = lane * 16;
#pragma unroll
        for (int q = 0; q < 4; ++q) {
            const float4 s0 = *(const float4*)(hwh + (size_t)b * 1024 + a0 + q * 4);
            hw[q * 4 + 0] = s0.x; hw[q * 4 + 1] = s0.y;
            hw[q * 4 + 2] = s0.z; hw[q * 4 + 3] = s0.w;
            const float4 vv = *(const float4*)(vvec + a0 + q * 4);
            vr[q * 4 + 0] = vv.x; vr[q * 4 + 1] = vv.y;
            vr[q * 4 + 2] = vv.z; vr[q * 4 + 3] = vv.w;
        }
        for (int n = w; n < kN; n += 16) {
            const ushort_t* fp = fprojbf + ((size_t)(b * kN + n)) * 1024 + lane * 16;
            const uint4 u0 = *(const uint4*)(fp);
            const uint4 u1 = *(const uint4*)(fp + 8);
            float p = 0.f;
            const uint_t uu[8] = {u0.x, u0.y, u0.z, u0.w, u1.x, u1.y, u1.z, u1.w};
#pragma unroll
            for (int q = 0; q < 8; ++q) {
                const float xa = __uint_as_float(uu[q] << 16);
                const float xb = __uint_as_float(uu[q] & 0xffff0000u);
                p += ftanh(xa + hw[2 * q]) * vr[2 * q];
                p += ftanh(xb + hw[2 * q + 1]) * vr[2 * q + 1];
            }
#pragma unroll
            for (int off = 32; off; off >>= 1) p += __shfl_down(p, off);
            if (lane == 0) scores_s[n] = p;
        }
    }
    __syncthreads();

    // ---- phase 2: softmax (all 1024 threads participate in barriers) ----
    const float val = (tid < kN) ? scores_s[tid] : -1e30f;
    float m = val;
#pragma unroll
    for (int off = 32; off; off >>= 1) m = fmaxf(m, __shfl_down(m, off));
    if (lane == 0) red[w] = m;
    __syncthreads();
    m = red[0];
#pragma unroll
    for (int i = 1; i < 16; ++i) m = fmaxf(m, red[i]);
    const float e = (tid < kN) ? __expf(val - m) : 0.f;
    float s = e;
#pragma unroll
    for (int off = 32; off; off >>= 1) s += __shfl_down(s, off);
    if (lane == 0) red[16 + w] = s;
    __syncthreads();
    s = red[16];
#pragma unroll
    for (int i = 1; i < 16; ++i) s += red[16 + i];
    if (tid < kN) alpha_s[tid] = e * (1.f / s);
    __syncthreads();

    // ---- phase 3: attn (tid < 512; same per-thread loop as before) ----
    if (tid < 512) {
        const int f0 = tid * 2;
        const ushort_t* fb = featsbf + (size_t)b * kN * 1024 + f0;
        float a0 = 0.f, a1 = 0.f;
#pragma unroll 4
        for (int n = 0; n < kN; ++n) {
            const uint_t u = *(const uint_t*)(fb + (size_t)n * 1024);
            a0 += alpha_s[n] * __uint_as_float(u << 16);
            a1 += alpha_s[n] * __uint_as_float(u & 0xffff0000u);
        }
        uint_t o = ((uint_t)f2bf(a1) << 16) | (uint_t)f2bf(a0);
        *(uint_t*)&attnbf[(size_t)b * 1024 + f0] = o;
    }
}

// ---------------------------------------------------------------------------
// Fallback scores / attn kernels (used only when workspace lacks featsbf)
// ---------------------------------------------------------------------------
__global__ __launch_bounds__(256) void scores_kernel(
    const ushort_t* __restrict__ fprojbf, const float* __restrict__ hwh,
    const float* __restrict__ vvec, float* __restrict__ scoresbuf)
{
    const int b = blockIdx.x, chunk = blockIdx.y;
    const int tid = threadIdx.x, lane = tid & 63, w = tid >> 6;

    float hw[16], vr[16];
    {
        const int a0 = lane * 16;
#pragma unroll
        for (int q = 0; q < 4; ++q) {
            const float4 s0 = *(const float4*)(hwh + (size_t)b * 1024 + a0 + q * 4);
            hw[q * 4 + 0] = s0.x; hw[q * 4 + 1] = s0.y;
            hw[q * 4 + 2] = s0.z; hw[q * 4 + 3] = s0.w;
            const float4 vv = *(const float4*)(vvec + a0 + q * 4);
            vr[q * 4 + 0] = vv.x; vr[q * 4 + 1] = vv.y;
            vr[q * 4 + 2] = vv.z; vr[q * 4 + 3] = vv.w;
        }
    }

#pragma unroll
    for (int i = 0; i < 7; ++i) {
        const int n = chunk * 28 + w * 7 + i;
        const ushort_t* fp = fprojbf + ((size_t)(b * kN + n)) * 1024 + lane * 16;
        const uint4 u0 = *(const uint4*)(fp);
        const uint4 u1 = *(const uint4*)(fp + 8);
        float p = 0.f;
        const uint_t uu[8] = {u0.x, u0.y, u0.z, u0.w, u1.x, u1.y, u1.z, u1.w};
#pragma unroll
        for (int q = 0; q < 8; ++q) {
            const float xa = __uint_as_float(uu[q] << 16);
            const float xb = __uint_as_float(uu[q] & 0xffff0000u);
            p += ftanh(xa + hw[2 * q]) * vr[2 * q];
            p += ftanh(xb + hw[2 * q + 1]) * vr[2 * q + 1];
        }
#pragma unroll
        for (int off = 32; off; off >>= 1) p += __shfl_down(p, off);
        if (lane == 0) scoresbuf[b * kN + n] = p;
    }
}

__global__ __launch_bounds__(256) void attn_kernel_f32(
    const float* __restrict__ scoresbuf, const float* __restrict__ featsf,
    ushort_t* __restrict__ attnbf)
{
    __shared__ float alpha_s[200];
    __shared__ float red[8];
    const int b = blockIdx.x;
    const int tid = threadIdx.x;

    const float val = (tid < kN) ? scoresbuf[b * kN + tid] : -1e30f;
    float m = val;
#pragma unroll
    for (int off = 32; off; off >>= 1) m = fmaxf(m, __shfl_down(m, off));
    if ((tid & 63) == 0) red[tid >> 6] = m;
    __syncthreads();
    m = fmaxf(fmaxf(red[0], red[1]), fmaxf(red[2], red[3]));
    const float e = (tid < kN) ? __expf(val - m) : 0.f;
    float s = e;
#pragma unroll
    for (int off = 32; off; off >>= 1) s += __shfl_down(s, off);
    if ((tid & 63) == 0) red[4 + (tid >> 6)] = s;
    __syncthreads();
    s = red[4] + red[5] + red[6] + red[7];
    if (tid < kN) alpha_s[tid] = e * (1.f / s);
    __syncthreads();

    const int f = blockIdx.y * 256 + tid;
    const float* fb = featsf + (size_t)b * kN * 1024 + f;
    float a = 0.f;
#pragma unroll 4
    for (int n = 0; n < kN; ++n) a += alpha_s[n] * fb[(size_t)n * 1024];
    attnbf[(size_t)b * 1024 + f] = f2bf(a);
}

// ---------------------------------------------------------------------------
// phase_gates: gates0 = [attn|emb_t](bf16) @ W0cat[4096,2048] + Ypart + bias
//   -> cell0 -> h(bf16), c(fp32). Tile 128M x 32N, BK=64 (32 serial iters).
// ---------------------------------------------------------------------------
__device__ __forceinline__ void phase_gates(
    char* arena, int job, int tstep,
    const ushort_t* __restrict__ attnbf, const ushort_t* __restrict__ embbf,
    const ushort_t* __restrict__ W0cat, const float* __restrict__ Ypart,
    const float* __restrict__ bih0, const float* __restrict__ bhh0,
    float* __restrict__ cbuf, ushort_t* __restrict__ hbf)
{
    ushort_t* xs  = (ushort_t*)arena;   // [2][128*72]
    ushort_t* ws2 = xs + 2 * 9216;      // [2][32*72]
    float*    eps = (float*)arena;      // [128*33], reused after K-loop

    const int tid = threadIdx.x;
    const int n0 = job * 32;
    const int lane = tid & 63, w = tid >> 6;
    const int wm = (w & 1) * 64, wn = (w >> 1) * 16;
    const int lr = lane & 15, quad = lane >> 4;

    const int arow = tid >> 1, acol = (tid & 1) * 32;
    const int wrow = tid >> 3, wcol = (tid & 7) * 8;

    f32x4 acc[4];
#pragma unroll
    for (int i = 0; i < 4; ++i) acc[i] = (f32x4){0.f, 0.f, 0.f, 0.f};

    uint4 xr[4], wr;
    auto LOAD = [&](int k0) {
        const ushort_t* srcbase = (k0 < 1024)
            ? (attnbf + (size_t)arow * 1024 + k0)
            : (embbf + ((size_t)arow * kT + tstep) * 1024 + (k0 - 1024));
#pragma unroll
        for (int j = 0; j < 4; ++j)
            xr[j] = *(const uint4*)(srcbase + acol + j * 8);
        wr = *(const uint4*)&W0cat[(size_t)(n0 + wrow) * 2048 + k0 + wcol];
    };
    auto WRITE = [&](int buf) {
#pragma unroll
        for (int j = 0; j < 4; ++j)
            *(uint4*)&xs[buf * 9216 + arow * 72 + acol + j * 8] = xr[j];
        *(uint4*)&ws2[buf * 2304 + wrow * 72 + wcol] = wr;
    };

    LOAD(0); WRITE(0); __syncthreads();
    int cur = 0;
    for (int k0 = 64; k0 <= 2048; k0 += 64) {
        const bool more = (k0 < 2048);
        if (more) LOAD(k0);
        bf16x8 af[2][4], bb[2];
#pragma unroll
        for (int ks = 0; ks < 2; ++ks) {
#pragma unroll
            for (int mf = 0; mf < 4; ++mf)
                af[ks][mf] = *(const bf16x8*)&xs[cur * 9216 + (wm + mf * 16 + lr) * 72 + ks * 32 + quad * 8];
            bb[ks] = *(const bf16x8*)&ws2[cur * 2304 + (wn + lr) * 72 + ks * 32 + quad * 8];
        }
#pragma unroll
        for (int ks = 0; ks < 2; ++ks)
#pragma unroll
            for (int mf = 0; mf < 4; ++mf)
                acc[mf] = __builtin_amdgcn_mfma_f32_16x16x32_bf16(
                    af[ks][mf], bb[ks], acc[mf], 0, 0, 0);
        if (more) WRITE(cur ^ 1);
        __syncthreads();
        cur ^= 1;
    }

#pragma unroll
    for (int mf = 0; mf < 4; ++mf)
#pragma unroll
        for (int r = 0; r < 4; ++r)
            eps[(wm + mf * 16 + quad * 4 + r) * 33 + wn + lr] = acc[mf][r];
    __syncthreads();

#pragma unroll
    for (int i = 0; i < 4; ++i) {
        const int cid = i * 256 + tid;
        const int b = cid & 127, ulc = cid >> 7;
        const int u = (n0 >> 2) + ulc;
        const int jb = n0 + ulc * 4;
        const float* yp = Ypart + (size_t)b * 4096 + jb;
        const float iv = fsigmoid(eps[b * 33 + ulc * 4 + 0] + yp[0] + bih0[u]        + bhh0[u]);
        const float fv = fsigmoid(eps[b * 33 + ulc * 4 + 1] + yp[1] + bih0[1024 + u] + bhh0[1024 + u]);
        const float gv = ftanh   (eps[b * 33 + ulc * 4 + 2] + yp[2] + bih0[2048 + u] + bhh0[2048 + u]);
        const float ov = fsigmoid(eps[b * 33 + ulc * 4 + 3] + yp[3] + bih0[3072 + u] + bhh0[3072 + u]);
        const float cp = cbuf[(size_t)b * 1024 + u];
        const float cn = fv * cp + iv * gv;
        cbuf[(size_t)b * 1024 + u] = cn;
        hbf[(size_t)b * 1024 + u] = f2bf(ov * ftanh(cn));
    }
}

__global__ __launch_bounds__(256) void gatesC(
    const ushort_t* __restrict__ attnbf, const ushort_t* __restrict__ embbf,
    const ushort_t* __restrict__ W0cat, const float* __restrict__ Ypart,
    const float* __restrict__ bih0, const float* __restrict__ bhh0,
    float* __restrict__ cbuf, ushort_t* __restrict__ hbf, int tstep)
{
    __shared__ alignas(16) char arena[ARENA_BYTES];
    phase_gates(arena, blockIdx.x, tstep, attnbf, embbf, W0cat, Ypart,
                bih0, bhh0, cbuf, hbf);
}

// ---------------------------------------------------------------------------
extern "C" void kernel_launch(void* const* d_in, const int* in_sizes, int n_in,
                              void* d_out, int out_size, void* d_ws, size_t ws_size,
                              hipStream_t stream)
{
    const float* feats = (const float*)d_in[0];
    const float* emb   = (const float*)d_in[1];
    const float* Wf    = (const float*)d_in[2];
    const float* Wh    = (const float*)d_in[3];
    const float* b_att = (const float*)d_in[4];
    const float* vvec  = (const float*)d_in[5];
    const float* Wih0  = (const float*)d_in[6];
    const float* Whh0  = (const float*)d_in[7];
    const float* bih0  = (const float*)d_in[8];
    const float* bhh0  = (const float*)d_in[9];
    const float* Wih1  = (const float*)d_in[10];
    const float* Whh1  = (const float*)d_in[11];
    const float* bih1  = (const float*)d_in[12];
    const float* bhh1  = (const float*)d_in[13];
    float* out = (float*)d_out;

    // workspace layout (ushort units first, then fp32)
    ushort_t* fprojbf = (ushort_t*)d_ws;                       // 25088*1024
    ushort_t* embbf   = fprojbf + (size_t)25088 * 1024;        // 4096*1024
    ushort_t* Wbig    = embbf   + (size_t)4096 * 1024;         // 9216*1024
    ushort_t* W0cat   = Wbig    + (size_t)9216 * 1024;         // 4096*2048
    ushort_t* WfT     = W0cat   + (size_t)4096 * 2048;         // 1024*1024
    ushort_t* hbf     = WfT     + (size_t)1024 * 1024;         // 128*1024
    ushort_t* attnbf  = hbf     + (size_t)128 * 1024;          // 128*1024
    float* hwh        = (float*)(attnbf + (size_t)128 * 1024); // 128*1024
    float* Ypart      = hwh   + (size_t)128 * 1024;            // 128*4096
    float* cbuf       = Ypart + (size_t)128 * 4096;            // 128*1024
    float* scoresbuf  = cbuf  + (size_t)128 * 1024;            // 128*196
    ushort_t* featsbf = (ushort_t*)(scoresbuf + 128 * 196);    // 25088*1024 (optional)

    const size_t need_full = 152668160;  // bytes incl. featsbf
    const bool use_bf = (ws_size >= need_full);

    // zero h, c
    hipMemsetAsync(hbf, 0, sizeof(ushort_t) * 128 * 1024, stream);
    hipMemsetAsync(cbuf, 0, sizeof(float) * 128 * 1024, stream);

    // pre-pass packs
    wf_transpose<<<dim3(16, 16), 256, 0, stream>>>(Wf, WfT);
    wf_transpose<<<dim3(16, 16), 256, 0, stream>>>(Wh, Wbig);  // rows 0..1023
    pack_whh0<<<4096, 256, 0, stream>>>(Whh0, Wbig);
    pack_w1sum<<<4096, 256, 0, stream>>>(Wih1, Whh1, Wbig);
    pack_w0cat<<<8192, 256, 0, stream>>>(Wih0, W0cat);
    cast_bf<<<4096, 256, 0, stream>>>(emb, embbf);
    if (use_bf) cast_bf<<<25088, 256, 0, stream>>>(feats, featsbf);

    // fproj (bf16) = feats @ Wf + b_att
    if (use_bf)
        fproj_mfma<1><<<dim3(8, 196), 256, 0, stream>>>(feats, featsbf, WfT, b_att, fprojbf);
    else
        fproj_mfma<0><<<dim3(8, 196), 256, 0, stream>>>(feats, featsbf, WfT, b_att, fprojbf);

    for (int t = 0; t < kT; ++t) {
        hgemm_A<<<144, 256, 0, stream>>>(hbf, Wbig, cbuf, bih1, bhh1,
                                         hwh, Ypart, out, t, 0);
        if (use_bf) {
            scores_attn<<<128, 1024, 0, stream>>>(fprojbf, hwh, vvec, featsbf, attnbf);
        } else {
            scores_kernel<<<dim3(128, 7), 256, 0, stream>>>(fprojbf, hwh, vvec, scoresbuf);
            attn_kernel_f32<<<dim3(128, 4), 256, 0, stream>>>(scoresbuf, feats, attnbf);
        }
        gatesC<<<128, 256, 0, stream>>>(attnbf, embbf, W0cat, Ypart,
                                        bih0, bhh0, cbuf, hbf, t);
    }
    // final cell1 for t=31 (uses h_32, c_32): only jobs 80..143 do useful work
    hgemm_A<<<64, 256, 0, stream>>>(hbf, Wbig, cbuf, bih1, bhh1,
                                    hwh, Ypart, out, kT, 80);

    (void)in_sizes; (void)n_in; (void)out_size; (void)ws_size;
}

// Round 5
// 2953.609 us; speedup vs baseline: 1.3706x; 1.3706x over previous
//
#include <hip/hip_runtime.h>
#include <cstddef>

typedef unsigned short ushort_t;
typedef unsigned int uint_t;
typedef __attribute__((ext_vector_type(8))) short bf16x8;
typedef __attribute__((ext_vector_type(4))) float f32x4;

constexpr int kB  = 128;
constexpr int kT  = 32;
constexpr int kN  = 196;
constexpr int kH  = 1024;

constexpr int ARENA_BYTES = 34816;  // hgemm BK=32 staging 30720 / eps 33280

__device__ __forceinline__ float fsigmoid(float x) { return 1.f / (1.f + __expf(-x)); }
__device__ __forceinline__ float ftanh(float x)    { return 1.f - 2.f / (__expf(2.f * x) + 1.f); }
__device__ __forceinline__ ushort_t f2bf(float f) {
    uint_t u = __float_as_uint(f);
    return (ushort_t)((u + 0x7fffu + ((u >> 16) & 1u)) >> 16);
}

// ---------------------------------------------------------------------------
// Pre-pass pack / cast kernels (unchanged)
// ---------------------------------------------------------------------------
__global__ __launch_bounds__(256) void wf_transpose(
    const float* __restrict__ Wsrc, ushort_t* __restrict__ dst)
{
    __shared__ float t[64][65];
    const int k0 = blockIdx.x * 64, a0 = blockIdx.y * 64;
    const int c = threadIdx.x & 15, r0 = threadIdx.x >> 4;
#pragma unroll
    for (int i = 0; i < 4; ++i) {
        const int r = r0 + i * 16;
        const float4 v = *(const float4*)(Wsrc + (size_t)(k0 + r) * 1024 + a0 + c * 4);
        t[r][c * 4 + 0] = v.x; t[r][c * 4 + 1] = v.y;
        t[r][c * 4 + 2] = v.z; t[r][c * 4 + 3] = v.w;
    }
    __syncthreads();
#pragma unroll
    for (int i = 0; i < 4; ++i) {
        const int r = r0 + i * 16;
        ushort4 h;
        h.x = f2bf(t[c * 4 + 0][r]); h.y = f2bf(t[c * 4 + 1][r]);
        h.z = f2bf(t[c * 4 + 2][r]); h.w = f2bf(t[c * 4 + 3][r]);
        *(ushort4*)&dst[(size_t)(a0 + r) * 1024 + k0 + c * 4] = h;
    }
}

__global__ __launch_bounds__(256) void pack_whh0(
    const float* __restrict__ Whh0, ushort_t* __restrict__ Wbig)
{
    const int idx = blockIdx.x * 256 + threadIdx.x;
    const int j = idx >> 8, k4 = (idx & 255) * 4;
    const int u = j >> 2, g = j & 3;
    const float4 v = *(const float4*)(Whh0 + (size_t)(g * 1024 + u) * 1024 + k4);
    ushort4 h;
    h.x = f2bf(v.x); h.y = f2bf(v.y); h.z = f2bf(v.z); h.w = f2bf(v.w);
    *(ushort4*)&Wbig[(size_t)(1024 + j) * 1024 + k4] = h;
}

__global__ __launch_bounds__(256) void pack_w1sum(
    const float* __restrict__ Wih1, const float* __restrict__ Whh1,
    ushort_t* __restrict__ Wbig)
{
    const int idx = blockIdx.x * 256 + threadIdx.x;
    const int j = idx >> 8, k4 = (idx & 255) * 4;
    const int u = j >> 2, g = j & 3;
    const size_t o = (size_t)(g * 1024 + u) * 1024 + k4;
    const float4 a = *(const float4*)(Wih1 + o);
    const float4 b = *(const float4*)(Whh1 + o);
    ushort4 h;
    h.x = f2bf(a.x + b.x); h.y = f2bf(a.y + b.y);
    h.z = f2bf(a.z + b.z); h.w = f2bf(a.w + b.w);
    *(ushort4*)&Wbig[(size_t)(5120 + j) * 1024 + k4] = h;
}

__global__ __launch_bounds__(256) void pack_w0cat(
    const float* __restrict__ Wih0, ushort_t* __restrict__ W0cat)
{
    const int idx = blockIdx.x * 256 + threadIdx.x;
    const int j = idx >> 9, k4 = (idx & 511) * 4;
    const int u = j >> 2, g = j & 3;
    const int srccol = (k4 < 1024) ? (k4 + 1024) : (k4 - 1024);
    const float4 v = *(const float4*)(Wih0 + (size_t)(g * 1024 + u) * 2048 + srccol);
    ushort4 h;
    h.x = f2bf(v.x); h.y = f2bf(v.y); h.z = f2bf(v.z); h.w = f2bf(v.w);
    *(ushort4*)&W0cat[(size_t)j * 2048 + k4] = h;
}

__global__ __launch_bounds__(256) void cast_bf(
    const float* __restrict__ src, ushort_t* __restrict__ dst)
{
    const size_t idx = ((size_t)blockIdx.x * 256 + threadIdx.x) * 4;
    const float4 v = *(const float4*)(src + idx);
    ushort4 h;
    h.x = f2bf(v.x); h.y = f2bf(v.y); h.z = f2bf(v.z); h.w = f2bf(v.w);
    *(ushort4*)&dst[idx] = h;
}

// ---------------------------------------------------------------------------
// fproj = bf16(feats @ Wf + b_att). 128x128 tile, BK=32, dbuf, single barrier.
// LDS-staged epilogue -> full-line stores. (round-3 version, measured 90us)
// ---------------------------------------------------------------------------
template<int BF>
__global__ __launch_bounds__(256) void fproj_mfma(
    const float* __restrict__ featsf, const ushort_t* __restrict__ featsbf,
    const ushort_t* __restrict__ WfT,
    const float* __restrict__ bias, ushort_t* __restrict__ fprojbf)
{
    __shared__ alignas(16) char farena[40960];
    ushort_t* As = (ushort_t*)farena;    // [2][128*40]
    ushort_t* Bs = As + 2 * 5120;        // [2][128*40]
    ushort_t* Cs = (ushort_t*)farena;    // [128][136] (reused after K-loop)

    const int tid = threadIdx.x;
    const int n0 = blockIdx.x * 128, m0 = blockIdx.y * 128;
    const int lane = tid & 63, w = tid >> 6;
    const int wm = (w & 1) * 64, wn = (w >> 1) * 64;
    const int lr = lane & 15, quad = lane >> 4;

    const int xrow0 = tid >> 2, xrow1 = 64 + (tid >> 2);
    const int xkc = (tid & 3) * 8;

    f32x4 acc[4][4];
#pragma unroll
    for (int i = 0; i < 4; ++i)
#pragma unroll
        for (int j = 0; j < 4; ++j)
            acc[i][j] = (f32x4){0.f, 0.f, 0.f, 0.f};

    uint4 a0r, a1r, b0r, b1r;
    float4 f00, f01, f10, f11;

    auto LOAD = [&](int k0) {
        if (BF) {
            a0r = *(const uint4*)&featsbf[(size_t)(m0 + xrow0) * 1024 + k0 + xkc];
            a1r = *(const uint4*)&featsbf[(size_t)(m0 + xrow1) * 1024 + k0 + xkc];
        } else {
            f00 = *(const float4*)&featsf[(size_t)(m0 + xrow0) * 1024 + k0 + xkc];
            f01 = *(const float4*)&featsf[(size_t)(m0 + xrow0) * 1024 + k0 + xkc + 4];
            f10 = *(const float4*)&featsf[(size_t)(m0 + xrow1) * 1024 + k0 + xkc];
            f11 = *(const float4*)&featsf[(size_t)(m0 + xrow1) * 1024 + k0 + xkc + 4];
        }
        b0r = *(const uint4*)&WfT[(size_t)(n0 + xrow0) * 1024 + k0 + xkc];
        b1r = *(const uint4*)&WfT[(size_t)(n0 + xrow1) * 1024 + k0 + xkc];
    };
    auto WRITE = [&](int buf) {
        if (BF) {
            *(uint4*)&As[buf * 5120 + xrow0 * 40 + xkc] = a0r;
            *(uint4*)&As[buf * 5120 + xrow1 * 40 + xkc] = a1r;
        } else {
            ushort4 h;
            h.x = f2bf(f00.x); h.y = f2bf(f00.y); h.z = f2bf(f00.z); h.w = f2bf(f00.w);
            *(ushort4*)&As[buf * 5120 + xrow0 * 40 + xkc] = h;
            h.x = f2bf(f01.x); h.y = f2bf(f01.y); h.z = f2bf(f01.z); h.w = f2bf(f01.w);
            *(ushort4*)&As[buf * 5120 + xrow0 * 40 + xkc + 4] = h;
            h.x = f2bf(f10.x); h.y = f2bf(f10.y); h.z = f2bf(f10.z); h.w = f2bf(f10.w);
            *(ushort4*)&As[buf * 5120 + xrow1 * 40 + xkc] = h;
            h.x = f2bf(f11.x); h.y = f2bf(f11.y); h.z = f2bf(f11.z); h.w = f2bf(f11.w);
            *(ushort4*)&As[buf * 5120 + xrow1 * 40 + xkc + 4] = h;
        }
        *(uint4*)&Bs[buf * 5120 + xrow0 * 40 + xkc] = b0r;
        *(uint4*)&Bs[buf * 5120 + xrow1 * 40 + xkc] = b1r;
    };

    LOAD(0); WRITE(0); __syncthreads();
    int cur = 0;
    for (int k0 = 32; k0 <= 1024; k0 += 32) {
        const bool more = (k0 < 1024);
        if (more) LOAD(k0);
        bf16x8 af[4], bb[4];
#pragma unroll
        for (int mf = 0; mf < 4; ++mf)
            af[mf] = *(const bf16x8*)&As[cur * 5120 + (wm + mf * 16 + lr) * 40 + quad * 8];
#pragma unroll
        for (int nf = 0; nf < 4; ++nf)
            bb[nf] = *(const bf16x8*)&Bs[cur * 5120 + (wn + nf * 16 + lr) * 40 + quad * 8];
#pragma unroll
        for (int mf = 0; mf < 4; ++mf)
#pragma unroll
            for (int nf = 0; nf < 4; ++nf)
                acc[mf][nf] = __builtin_amdgcn_mfma_f32_16x16x32_bf16(
                    af[mf], bb[nf], acc[mf][nf], 0, 0, 0);
        if (more) WRITE(cur ^ 1);
        __syncthreads();
        cur ^= 1;
    }

#pragma unroll
    for (int nf = 0; nf < 4; ++nf) {
        const int n = wn + nf * 16 + lr;
        const float bn = bias[n0 + n];
#pragma unroll
        for (int mf = 0; mf < 4; ++mf)
#pragma unroll
            for (int r = 0; r < 4; ++r) {
                const int m = wm + mf * 16 + quad * 4 + r;
                Cs[m * 136 + n] = f2bf(acc[mf][nf][r] + bn);
            }
    }
    __syncthreads();
#pragma unroll
    for (int p = 0; p < 8; ++p) {
        const int row = p * 16 + (tid >> 4);
        const int c8 = (tid & 15) * 8;
        const uint4 v = *(const uint4*)&Cs[row * 136 + c8];
        *(uint4*)&fprojbf[(size_t)(m0 + row) * 1024 + n0 + c8] = v;
    }
}

// ---------------------------------------------------------------------------
// Yemb[(b*kT+t)][j] = emb(b,t) @ Wih0_embpart  (one-time pre-pass GEMM)
// A = embbf [4096][1024] bf16; B rows = W0cat[j][1024 + k] (stride 2048).
// 128x128 tile, BK=32, dbuf, f32 output. grid (32 n-tiles, 32 m-tiles).
// ---------------------------------------------------------------------------
__global__ __launch_bounds__(256) void yemb_mfma(
    const ushort_t* __restrict__ embbf, const ushort_t* __restrict__ W0cat,
    float* __restrict__ Yemb)
{
    __shared__ alignas(16) char farena[40960];
    ushort_t* As = (ushort_t*)farena;    // [2][128*40]
    ushort_t* Bs = As + 2 * 5120;        // [2][128*40]

    const int tid = threadIdx.x;
    const int n0 = blockIdx.x * 128, m0 = blockIdx.y * 128;
    const int lane = tid & 63, w = tid >> 6;
    const int wm = (w & 1) * 64, wn = (w >> 1) * 64;
    const int lr = lane & 15, quad = lane >> 4;

    const int xrow0 = tid >> 2, xrow1 = 64 + (tid >> 2);
    const int xkc = (tid & 3) * 8;

    f32x4 acc[4][4];
#pragma unroll
    for (int i = 0; i < 4; ++i)
#pragma unroll
        for (int j = 0; j < 4; ++j)
            acc[i][j] = (f32x4){0.f, 0.f, 0.f, 0.f};

    uint4 a0r, a1r, b0r, b1r;
    auto LOAD = [&](int k0) {
        a0r = *(const uint4*)&embbf[(size_t)(m0 + xrow0) * 1024 + k0 + xkc];
        a1r = *(const uint4*)&embbf[(size_t)(m0 + xrow1) * 1024 + k0 + xkc];
        b0r = *(const uint4*)&W0cat[(size_t)(n0 + xrow0) * 2048 + 1024 + k0 + xkc];
        b1r = *(const uint4*)&W0cat[(size_t)(n0 + xrow1) * 2048 + 1024 + k0 + xkc];
    };
    auto WRITE = [&](int buf) {
        *(uint4*)&As[buf * 5120 + xrow0 * 40 + xkc] = a0r;
        *(uint4*)&As[buf * 5120 + xrow1 * 40 + xkc] = a1r;
        *(uint4*)&Bs[buf * 5120 + xrow0 * 40 + xkc] = b0r;
        *(uint4*)&Bs[buf * 5120 + xrow1 * 40 + xkc] = b1r;
    };

    LOAD(0); WRITE(0); __syncthreads();
    int cur = 0;
    for (int k0 = 32; k0 <= 1024; k0 += 32) {
        const bool more = (k0 < 1024);
        if (more) LOAD(k0);
        bf16x8 af[4], bb[4];
#pragma unroll
        for (int mf = 0; mf < 4; ++mf)
            af[mf] = *(const bf16x8*)&As[cur * 5120 + (wm + mf * 16 + lr) * 40 + quad * 8];
#pragma unroll
        for (int nf = 0; nf < 4; ++nf)
            bb[nf] = *(const bf16x8*)&Bs[cur * 5120 + (wn + nf * 16 + lr) * 40 + quad * 8];
#pragma unroll
        for (int mf = 0; mf < 4; ++mf)
#pragma unroll
            for (int nf = 0; nf < 4; ++nf)
                acc[mf][nf] = __builtin_amdgcn_mfma_f32_16x16x32_bf16(
                    af[mf], bb[nf], acc[mf][nf], 0, 0, 0);
        if (more) WRITE(cur ^ 1);
        __syncthreads();
        cur ^= 1;
    }

#pragma unroll
    for (int mf = 0; mf < 4; ++mf)
#pragma unroll
        for (int nf = 0; nf < 4; ++nf)
#pragma unroll
            for (int r = 0; r < 4; ++r) {
                const int m = m0 + wm + mf * 16 + quad * 4 + r;
                const int n = n0 + wn + nf * 16 + lr;
                Yemb[(size_t)m * 4096 + n] = acc[mf][nf][r];
            }
}

// ---------------------------------------------------------------------------
// phase_hgemm: Y = h_t(bf16) @ Wbig[9216,1024]^rowmajor. Tile 128M x 64N,
// BK=32, dbuf, single barrier per iter. (round-2 proven version)
// ---------------------------------------------------------------------------
__device__ __forceinline__ void phase_hgemm(
    char* arena, int job, int tstep,
    const ushort_t* __restrict__ hbf, const ushort_t* __restrict__ Wbig,
    const float* __restrict__ cbuf,
    const float* __restrict__ bih1, const float* __restrict__ bhh1,
    float* __restrict__ hwh, float* __restrict__ Ypart,
    float* __restrict__ out)
{
    ushort_t* xs  = (ushort_t*)arena;   // [2][5120]
    ushort_t* wsB = xs + 10240;         // [2][2560]
    float*    eps = (float*)arena;      // [128*65], reused after K-loop

    const int tid = threadIdx.x;
    const int n0 = job * 64;
    const int lane = tid & 63, w = tid >> 6;
    const int wm = (w & 1) * 64, wn = (w >> 1) * 32;
    const int lr = lane & 15, quad = lane >> 4;

    const int xrow0 = tid >> 2, xrow1 = 64 + (tid >> 2);
    const int xkc = (tid & 3) * 8;

    f32x4 acc[4][2];
#pragma unroll
    for (int i = 0; i < 4; ++i) {
        acc[i][0] = (f32x4){0.f, 0.f, 0.f, 0.f};
        acc[i][1] = (f32x4){0.f, 0.f, 0.f, 0.f};
    }

    uint4 x0r, x1r, w0r;
    auto LOAD = [&](int k0) {
        x0r = *(const uint4*)&hbf[(size_t)xrow0 * 1024 + k0 + xkc];
        x1r = *(const uint4*)&hbf[(size_t)xrow1 * 1024 + k0 + xkc];
        w0r = *(const uint4*)&Wbig[(size_t)(n0 + xrow0) * 1024 + k0 + xkc];
    };
    auto WRITE = [&](int buf) {
        *(uint4*)&xs[buf * 5120 + xrow0 * 40 + xkc] = x0r;
        *(uint4*)&xs[buf * 5120 + xrow1 * 40 + xkc] = x1r;
        *(uint4*)&wsB[buf * 2560 + xrow0 * 40 + xkc] = w0r;
    };

    LOAD(0); WRITE(0); __syncthreads();
    int cur = 0;
    for (int k0 = 32; k0 <= 1024; k0 += 32) {
        const bool more = (k0 < 1024);
        if (more) LOAD(k0);
        bf16x8 af[4], bb[2];
#pragma unroll
        for (int mf = 0; mf < 4; ++mf)
            af[mf] = *(const bf16x8*)&xs[cur * 5120 + (wm + mf * 16 + lr) * 40 + quad * 8];
#pragma unroll
        for (int nf = 0; nf < 2; ++nf)
            bb[nf] = *(const bf16x8*)&wsB[cur * 2560 + (wn + nf * 16 + lr) * 40 + quad * 8];
#pragma unroll
        for (int mf = 0; mf < 4; ++mf)
#pragma unroll
            for (int nf = 0; nf < 2; ++nf)
                acc[mf][nf] = __builtin_amdgcn_mfma_f32_16x16x32_bf16(
                    af[mf], bb[nf], acc[mf][nf], 0, 0, 0);
        if (more) WRITE(cur ^ 1);
        __syncthreads();
        cur ^= 1;
    }

    if (n0 < 5120) {
        float* dst = (n0 < 1024) ? hwh : Ypart;
        const int stride = (n0 < 1024) ? 1024 : 4096;
        const int nbase = (n0 < 1024) ? n0 : (n0 - 1024);
#pragma unroll
        for (int mf = 0; mf < 4; ++mf)
#pragma unroll
            for (int nf = 0; nf < 2; ++nf)
#pragma unroll
                for (int r = 0; r < 4; ++r) {
                    const int m = wm + mf * 16 + quad * 4 + r;
                    const int n = nbase + wn + nf * 16 + lr;
                    dst[(size_t)m * stride + n] = acc[mf][nf][r];
                }
    } else {
#pragma unroll
        for (int mf = 0; mf < 4; ++mf)
#pragma unroll
            for (int nf = 0; nf < 2; ++nf)
#pragma unroll
                for (int r = 0; r < 4; ++r)
                    eps[(wm + mf * 16 + quad * 4 + r) * 65 + (wn + nf * 16 + lr)] = acc[mf][nf][r];
        __syncthreads();
        if (tstep >= 1) {
#pragma unroll
            for (int i = 0; i < 8; ++i) {
                const int cid = i * 256 + tid;
                const int b = cid & 127, ulc = cid >> 7;
                const int u = ((n0 - 5120) >> 2) + ulc;
                const float iv = fsigmoid(eps[b * 65 + ulc * 4 + 0] + bih1[u]        + bhh1[u]);
                const float fv = fsigmoid(eps[b * 65 + ulc * 4 + 1] + bih1[1024 + u] + bhh1[1024 + u]);
                const float gv = ftanh   (eps[b * 65 + ulc * 4 + 2] + bih1[2048 + u] + bhh1[2048 + u]);
                const float ov = fsigmoid(eps[b * 65 + ulc * 4 + 3] + bih1[3072 + u] + bhh1[3072 + u]);
                const float cp = cbuf[(size_t)b * 1024 + u];
                const float cn = fv * cp + iv * gv;
                out[((size_t)b * kT + (tstep - 1)) * 1024 + u] = ov * ftanh(cn);
            }
        }
    }
}

__global__ __launch_bounds__(256) void hgemm_A(
    const ushort_t* __restrict__ hbf, const ushort_t* __restrict__ Wbig,
    const float* __restrict__ cbuf,
    const float* __restrict__ bih1, const float* __restrict__ bhh1,
    float* __restrict__ hwh, float* __restrict__ Ypart,
    float* __restrict__ out, int tstep, int job_base)
{
    __shared__ alignas(16) char arena[ARENA_BYTES];
    phase_hgemm(arena, blockIdx.x + job_base, tstep, hbf, Wbig, cbuf,
                bih1, bhh1, hwh, Ypart, out);
}

// ---------------------------------------------------------------------------
// scores[b,n] = sum_a tanh(fprojbf[b,n,a] + hwh[b,a]) * v[a].  grid (128,7).
// ---------------------------------------------------------------------------
__global__ __launch_bounds__(256) void scores_kernel(
    const ushort_t* __restrict__ fprojbf, const float* __restrict__ hwh,
    const float* __restrict__ vvec, float* __restrict__ scoresbuf)
{
    const int b = blockIdx.x, chunk = blockIdx.y;
    const int tid = threadIdx.x, lane = tid & 63, w = tid >> 6;

    float hw[16], vr[16];
    {
        const int a0 = lane * 16;
#pragma unroll
        for (int q = 0; q < 4; ++q) {
            const float4 s0 = *(const float4*)(hwh + (size_t)b * 1024 + a0 + q * 4);
            hw[q * 4 + 0] = s0.x; hw[q * 4 + 1] = s0.y;
            hw[q * 4 + 2] = s0.z; hw[q * 4 + 3] = s0.w;
            const float4 vv = *(const float4*)(vvec + a0 + q * 4);
            vr[q * 4 + 0] = vv.x; vr[q * 4 + 1] = vv.y;
            vr[q * 4 + 2] = vv.z; vr[q * 4 + 3] = vv.w;
        }
    }

#pragma unroll
    for (int i = 0; i < 7; ++i) {
        const int n = chunk * 28 + w * 7 + i;
        const ushort_t* fp = fprojbf + ((size_t)(b * kN + n)) * 1024 + lane * 16;
        const uint4 u0 = *(const uint4*)(fp);
        const uint4 u1 = *(const uint4*)(fp + 8);
        float p = 0.f;
        const uint_t uu[8] = {u0.x, u0.y, u0.z, u0.w, u1.x, u1.y, u1.z, u1.w};
#pragma unroll
        for (int q = 0; q < 8; ++q) {
            const float xa = __uint_as_float(uu[q] << 16);
            const float xb = __uint_as_float(uu[q] & 0xffff0000u);
            p += ftanh(xa + hw[2 * q]) * vr[2 * q];
            p += ftanh(xb + hw[2 * q + 1]) * vr[2 * q + 1];
        }
#pragma unroll
        for (int off = 32; off; off >>= 1) p += __shfl_down(p, off);
        if (lane == 0) scoresbuf[b * kN + n] = p;
    }
}

// ---------------------------------------------------------------------------
// softmax (per-block recompute) + attn -> attnbf.  BF=1: grid (128,2);
// BF=0: fp32 feats, grid (128,4).
// ---------------------------------------------------------------------------
template<int BF>
__global__ __launch_bounds__(256) void attn_kernel(
    const float* __restrict__ scoresbuf, const float* __restrict__ featsf,
    const ushort_t* __restrict__ featsbf, ushort_t* __restrict__ attnbf)
{
    __shared__ float alpha_s[200];
    __shared__ float red[8];
    const int b = blockIdx.x;
    const int tid = threadIdx.x;

    const float val = (tid < kN) ? scoresbuf[b * kN + tid] : -1e30f;
    float m = val;
#pragma unroll
    for (int off = 32; off; off >>= 1) m = fmaxf(m, __shfl_down(m, off));
    if ((tid & 63) == 0) red[tid >> 6] = m;
    __syncthreads();
    m = fmaxf(fmaxf(red[0], red[1]), fmaxf(red[2], red[3]));
    const float e = (tid < kN) ? __expf(val - m) : 0.f;
    float s = e;
#pragma unroll
    for (int off = 32; off; off >>= 1) s += __shfl_down(s, off);
    if ((tid & 63) == 0) red[4 + (tid >> 6)] = s;
    __syncthreads();
    s = red[4] + red[5] + red[6] + red[7];
    if (tid < kN) alpha_s[tid] = e * (1.f / s);
    __syncthreads();

    if (BF) {
        const int f0 = blockIdx.y * 512 + tid * 2;
        const ushort_t* fb = featsbf + (size_t)b * kN * 1024 + f0;
        float a0 = 0.f, a1 = 0.f;
#pragma unroll 4
        for (int n = 0; n < kN; ++n) {
            const uint_t u = *(const uint_t*)(fb + (size_t)n * 1024);
            a0 += alpha_s[n] * __uint_as_float(u << 16);
            a1 += alpha_s[n] * __uint_as_float(u & 0xffff0000u);
        }
        uint_t o = ((uint_t)f2bf(a1) << 16) | (uint_t)f2bf(a0);
        *(uint_t*)&attnbf[(size_t)b * 1024 + f0] = o;
    } else {
        const int f = blockIdx.y * 256 + tid;
        const float* fb = featsf + (size_t)b * kN * 1024 + f;
        float a = 0.f;
#pragma unroll 4
        for (int n = 0; n < kN; ++n) a += alpha_s[n] * fb[(size_t)n * 1024];
        attnbf[(size_t)b * 1024 + f] = f2bf(a);
    }
}

// ---------------------------------------------------------------------------
// phase_gates (templated): EMB=1 -> K=2048 over [attn|emb_t] (round-2 path);
// EMB=0 -> K=1024 over attn only, Yemb added in epilogue.
// Tile 128M x 32N, BK=32, dbuf, single barrier. grid 128.
// ---------------------------------------------------------------------------
template<int EMB>
__device__ __forceinline__ void phase_gates(
    char* arena, int job, int tstep,
    const ushort_t* __restrict__ attnbf, const ushort_t* __restrict__ embbf,
    const ushort_t* __restrict__ W0cat, const float* __restrict__ Ypart,
    const float* __restrict__ Yemb,
    const float* __restrict__ bih0, const float* __restrict__ bhh0,
    float* __restrict__ cbuf, ushort_t* __restrict__ hbf)
{
    ushort_t* xs  = (ushort_t*)arena;   // [2][5120]
    ushort_t* ws2 = xs + 10240;         // [2][1280]
    float*    eps = (float*)arena;      // [128*33], reused after K-loop

    const int tid = threadIdx.x;
    const int n0 = job * 32;
    const int lane = tid & 63, w = tid >> 6;
    const int wm = (w & 1) * 64, wn = (w >> 1) * 16;
    const int lr = lane & 15, quad = lane >> 4;

    const int xrow0 = tid >> 2, xrow1 = 64 + (tid >> 2);
    const int xkc = (tid & 3) * 8;
    const int wrow = tid >> 3, wkc = (tid & 7) * 4;

    constexpr int KMAX = EMB ? 2048 : 1024;

    f32x4 acc[4];
#pragma unroll
    for (int i = 0; i < 4; ++i) acc[i] = (f32x4){0.f, 0.f, 0.f, 0.f};

    uint4 x0r, x1r; uint2 w0r;
    auto LOAD = [&](int k0) {
        const ushort_t* s0 = (!EMB || k0 < 1024)
            ? (attnbf + (size_t)xrow0 * 1024 + k0)
            : (embbf + ((size_t)xrow0 * kT + tstep) * 1024 + (k0 - 1024));
        const ushort_t* s1 = (!EMB || k0 < 1024)
            ? (attnbf + (size_t)xrow1 * 1024 + k0)
            : (embbf + ((size_t)xrow1 * kT + tstep) * 1024 + (k0 - 1024));
        x0r = *(const uint4*)(s0 + xkc);
        x1r = *(const uint4*)(s1 + xkc);
        w0r = *(const uint2*)&W0cat[(size_t)(n0 + wrow) * 2048 + k0 + wkc];
    };
    auto WRITE = [&](int buf) {
        *(uint4*)&xs[buf * 5120 + xrow0 * 40 + xkc] = x0r;
        *(uint4*)&xs[buf * 5120 + xrow1 * 40 + xkc] = x1r;
        *(uint2*)&ws2[buf * 1280 + wrow * 40 + wkc] = w0r;
    };

    LOAD(0); WRITE(0); __syncthreads();
    int cur = 0;
    for (int k0 = 32; k0 <= KMAX; k0 += 32) {
        const bool more = (k0 < KMAX);
        if (more) LOAD(k0);
        bf16x8 af[4], bb;
#pragma unroll
        for (int mf = 0; mf < 4; ++mf)
            af[mf] = *(const bf16x8*)&xs[cur * 5120 + (wm + mf * 16 + lr) * 40 + quad * 8];
        bb = *(const bf16x8*)&ws2[cur * 1280 + (wn + lr) * 40 + quad * 8];
#pragma unroll
        for (int mf = 0; mf < 4; ++mf)
            acc[mf] = __builtin_amdgcn_mfma_f32_16x16x32_bf16(
                af[mf], bb, acc[mf], 0, 0, 0);
        if (more) WRITE(cur ^ 1);
        __syncthreads();
        cur ^= 1;
    }

#pragma unroll
    for (int mf = 0; mf < 4; ++mf)
#pragma unroll
        for (int r = 0; r < 4; ++r)
            eps[(wm + mf * 16 + quad * 4 + r) * 33 + wn + lr] = acc[mf][r];
    __syncthreads();

#pragma unroll
    for (int i = 0; i < 4; ++i) {
        const int cid = i * 256 + tid;
        const int b = cid & 127, ulc = cid >> 7;
        const int u = (n0 >> 2) + ulc;
        const int jb = n0 + ulc * 4;
        const float* yp = Ypart + (size_t)b * 4096 + jb;
        float e0 = eps[b * 33 + ulc * 4 + 0] + yp[0];
        float e1 = eps[b * 33 + ulc * 4 + 1] + yp[1];
        float e2 = eps[b * 33 + ulc * 4 + 2] + yp[2];
        float e3 = eps[b * 33 + ulc * 4 + 3] + yp[3];
        if (!EMB) {
            const float* ye = Yemb + ((size_t)b * kT + tstep) * 4096 + jb;
            e0 += ye[0]; e1 += ye[1]; e2 += ye[2]; e3 += ye[3];
        }
        const float iv = fsigmoid(e0 + bih0[u]        + bhh0[u]);
        const float fv = fsigmoid(e1 + bih0[1024 + u] + bhh0[1024 + u]);
        const float gv = ftanh   (e2 + bih0[2048 + u] + bhh0[2048 + u]);
        const float ov = fsigmoid(e3 + bih0[3072 + u] + bhh0[3072 + u]);
        const float cp = cbuf[(size_t)b * 1024 + u];
        const float cn = fv * cp + iv * gv;
        cbuf[(size_t)b * 1024 + u] = cn;
        hbf[(size_t)b * 1024 + u] = f2bf(ov * ftanh(cn));
    }
}

template<int EMB>
__global__ __launch_bounds__(256) void gatesC(
    const ushort_t* __restrict__ attnbf, const ushort_t* __restrict__ embbf,
    const ushort_t* __restrict__ W0cat, const float* __restrict__ Ypart,
    const float* __restrict__ Yemb,
    const float* __restrict__ bih0, const float* __restrict__ bhh0,
    float* __restrict__ cbuf, ushort_t* __restrict__ hbf, int tstep)
{
    __shared__ alignas(16) char arena[ARENA_BYTES];
    phase_gates<EMB>(arena, blockIdx.x, tstep, attnbf, embbf, W0cat, Ypart,
                     Yemb, bih0, bhh0, cbuf, hbf);
}

// ---------------------------------------------------------------------------
extern "C" void kernel_launch(void* const* d_in, const int* in_sizes, int n_in,
                              void* d_out, int out_size, void* d_ws, size_t ws_size,
                              hipStream_t stream)
{
    const float* feats = (const float*)d_in[0];
    const float* emb   = (const float*)d_in[1];
    const float* Wf    = (const float*)d_in[2];
    const float* Wh    = (const float*)d_in[3];
    const float* b_att = (const float*)d_in[4];
    const float* vvec  = (const float*)d_in[5];
    const float* Wih0  = (const float*)d_in[6];
    const float* Whh0  = (const float*)d_in[7];
    const float* bih0  = (const float*)d_in[8];
    const float* bhh0  = (const float*)d_in[9];
    const float* Wih1  = (const float*)d_in[10];
    const float* Whh1  = (const float*)d_in[11];
    const float* bih1  = (const float*)d_in[12];
    const float* bhh1  = (const float*)d_in[13];
    float* out = (float*)d_out;

    // workspace layout (ushort units first, then fp32)
    ushort_t* fprojbf = (ushort_t*)d_ws;                       // 25088*1024
    ushort_t* embbf   = fprojbf + (size_t)25088 * 1024;        // 4096*1024
    ushort_t* Wbig    = embbf   + (size_t)4096 * 1024;         // 9216*1024
    ushort_t* W0cat   = Wbig    + (size_t)9216 * 1024;         // 4096*2048
    ushort_t* WfT     = W0cat   + (size_t)4096 * 2048;         // 1024*1024
    ushort_t* hbf     = WfT     + (size_t)1024 * 1024;         // 128*1024
    ushort_t* attnbf  = hbf     + (size_t)128 * 1024;          // 128*1024
    float* hwh        = (float*)(attnbf + (size_t)128 * 1024); // 128*1024
    float* Ypart      = hwh   + (size_t)128 * 1024;            // 128*4096
    float* cbuf       = Ypart + (size_t)128 * 4096;            // 128*1024
    float* scoresbuf  = cbuf  + (size_t)128 * 1024;            // 128*196
    ushort_t* featsbf = (ushort_t*)(scoresbuf + 128 * 196);    // 25088*1024 (optional)
    float* Yemb       = (float*)(featsbf + (size_t)25088 * 1024); // 4096*4096 f32 (optional)

    const size_t need_full = 152668160;               // bytes incl. featsbf
    const size_t need_yemb = need_full + (size_t)4096 * 4096 * 4;  // + 64 MB
    const bool use_bf   = (ws_size >= need_full);
    const bool use_yemb = use_bf && (ws_size >= need_yemb);

    // zero h, c
    hipMemsetAsync(hbf, 0, sizeof(ushort_t) * 128 * 1024, stream);
    hipMemsetAsync(cbuf, 0, sizeof(float) * 128 * 1024, stream);

    // pre-pass packs
    wf_transpose<<<dim3(16, 16), 256, 0, stream>>>(Wf, WfT);
    wf_transpose<<<dim3(16, 16), 256, 0, stream>>>(Wh, Wbig);  // rows 0..1023
    pack_whh0<<<4096, 256, 0, stream>>>(Whh0, Wbig);
    pack_w1sum<<<4096, 256, 0, stream>>>(Wih1, Whh1, Wbig);
    pack_w0cat<<<8192, 256, 0, stream>>>(Wih0, W0cat);
    cast_bf<<<4096, 256, 0, stream>>>(emb, embbf);
    if (use_bf) cast_bf<<<25088, 256, 0, stream>>>(feats, featsbf);

    // fproj (bf16) = feats @ Wf + b_att
    if (use_bf)
        fproj_mfma<1><<<dim3(8, 196), 256, 0, stream>>>(feats, featsbf, WfT, b_att, fprojbf);
    else
        fproj_mfma<0><<<dim3(8, 196), 256, 0, stream>>>(feats, featsbf, WfT, b_att, fprojbf);

    // one-time Yemb = emb @ Wih0_embpart (f32)
    if (use_yemb)
        yemb_mfma<<<dim3(32, 32), 256, 0, stream>>>(embbf, W0cat, Yemb);

    for (int t = 0; t < kT; ++t) {
        hgemm_A<<<144, 256, 0, stream>>>(hbf, Wbig, cbuf, bih1, bhh1,
                                         hwh, Ypart, out, t, 0);
        scores_kernel<<<dim3(128, 7), 256, 0, stream>>>(fprojbf, hwh, vvec, scoresbuf);
        if (use_bf)
            attn_kernel<1><<<dim3(128, 2), 256, 0, stream>>>(scoresbuf, feats, featsbf, attnbf);
        else
            attn_kernel<0><<<dim3(128, 4), 256, 0, stream>>>(scoresbuf, feats, featsbf, attnbf);
        if (use_yemb)
            gatesC<0><<<128, 256, 0, stream>>>(attnbf, embbf, W0cat, Ypart, Yemb,
                                               bih0, bhh0, cbuf, hbf, t);
        else
            gatesC<1><<<128, 256, 0, stream>>>(attnbf, embbf, W0cat, Ypart, Yemb,
                                               bih0, bhh0, cbuf, hbf, t);
    }
    // final cell1 for t=31 (uses h_32, c_32): only jobs 80..143 do useful work
    hgemm_A<<<64, 256, 0, stream>>>(hbf, Wbig, cbuf, bih1, bhh1,
                                    hwh, Ypart, out, kT, 80);

    (void)in_sizes; (void)n_in; (void)out_size; (void)ws_size;
}